// Round 1
// baseline (457.740 us; speedup 1.0000x reference)
//
#include <hip/hip_runtime.h>

#define D_IN   4096
#define D_OUT  4096
#define N_TOK  8192
#define RANK   16
#define NEXP   8
#define ER     128          // NEXP*RANK — lora inner width
#define SCALING 2.0f        // 32/16

typedef __attribute__((ext_vector_type(8))) short short8;     // 8 bf16 (4 VGPR)
typedef __attribute__((ext_vector_type(4))) float f32x4;
typedef __attribute__((ext_vector_type(4))) unsigned short us4;

__device__ __forceinline__ unsigned short f2bf(float f) {
  unsigned u = __float_as_uint(f);
  u += 0x7FFFu + ((u >> 16) & 1u);     // RNE
  return (unsigned short)(u >> 16);
}

__device__ __forceinline__ void gload_lds16(const void* g, void* l) {
  __builtin_amdgcn_global_load_lds(
      (const __attribute__((address_space(1))) unsigned int*)g,
      (__attribute__((address_space(3))) unsigned int*)l, 16, 0, 0);
}

// ---------------- kernel 1: weight conversions --------------------------
// Wb[o][k] = bf16(W_base[o][k]); Ab[e*16+r][k] = bf16(A_stack[e][r][k]) (linear);
// Bcb[o][e*16+r] = bf16(B_stack[e][o][r])
__global__ void prep_kernel(const float* __restrict__ W, const float* __restrict__ A,
                            const float* __restrict__ B,
                            unsigned short* __restrict__ Wb,
                            unsigned short* __restrict__ Ab,
                            unsigned short* __restrict__ Bcb) {
  const int NW4 = (D_OUT * D_IN) / 4;     // 4194304
  const int NA4 = (ER * D_IN) / 4;        // 131072
  const int NB4 = (D_OUT * ER) / 4;       // 131072
  const int total = NW4 + NA4 + NB4;
  for (int i = blockIdx.x * blockDim.x + threadIdx.x; i < total;
       i += gridDim.x * blockDim.x) {
    if (i < NW4) {
      float4 v = ((const float4*)W)[i];
      us4 o = { f2bf(v.x), f2bf(v.y), f2bf(v.z), f2bf(v.w) };
      ((us4*)Wb)[i] = o;
    } else if (i < NW4 + NA4) {
      int j = i - NW4;
      float4 v = ((const float4*)A)[j];
      us4 o = { f2bf(v.x), f2bf(v.y), f2bf(v.z), f2bf(v.w) };
      ((us4*)Ab)[j] = o;
    } else {
      int j = i - NW4 - NA4;              // out float4 idx = o*32 + e*4 + rq
      int o = j >> 5; int rem = j & 31; int e = rem >> 2; int rq = rem & 3;
      float4 v = *(const float4*)(B + (size_t)e * D_OUT * RANK + o * RANK + rq * 4);
      us4 ob = { f2bf(v.x), f2bf(v.y), f2bf(v.z), f2bf(v.w) };
      ((us4*)Bcb)[j] = ob;
    }
  }
}

// ---------------- kernel 2: x->bf16 + f32 router + top-2 combine --------
// One wave handles 4 tokens; lanes partition K. Logits in exact f32.
__global__ __launch_bounds__(256) void router_kernel(
    const float* __restrict__ X, const float* __restrict__ Wr,
    unsigned short* __restrict__ Xb, float* __restrict__ Comb) {
  int wave = threadIdx.x >> 6, lane = threadIdx.x & 63;
  int tok0 = blockIdx.x * 16 + wave * 4;
  float acc[4][8];
#pragma unroll
  for (int t = 0; t < 4; ++t)
#pragma unroll
    for (int e = 0; e < 8; ++e) acc[t][e] = 0.f;
  const float4* X4 = (const float4*)X;
  const float4* W4 = (const float4*)Wr;
#pragma unroll 1
  for (int it = 0; it < 16; ++it) {
    int kq = it * 64 + lane;             // float4 index within a 1024-float4 row
    float4 w[8];
#pragma unroll
    for (int e = 0; e < 8; ++e) w[e] = W4[e * 1024 + kq];
#pragma unroll
    for (int t = 0; t < 4; ++t) {
      float4 xv = X4[(size_t)(tok0 + t) * 1024 + kq];
      us4 xb = { f2bf(xv.x), f2bf(xv.y), f2bf(xv.z), f2bf(xv.w) };
      ((us4*)Xb)[(size_t)(tok0 + t) * 1024 + kq] = xb;
#pragma unroll
      for (int e = 0; e < 8; ++e)
        acc[t][e] = fmaf(xv.x, w[e].x, fmaf(xv.y, w[e].y,
                     fmaf(xv.z, w[e].z, fmaf(xv.w, w[e].w, acc[t][e]))));
    }
  }
  // butterfly reduce over 64 lanes — every lane ends with full sums
#pragma unroll
  for (int t = 0; t < 4; ++t)
#pragma unroll
    for (int e = 0; e < 8; ++e) {
      float v = acc[t][e];
      for (int off = 32; off; off >>= 1) v += __shfl_xor(v, off, 64);
      acc[t][e] = v;
    }
#pragma unroll
  for (int t = 0; t < 4; ++t) {
    float m1 = acc[t][0]; int i1 = 0;
#pragma unroll
    for (int e = 1; e < 8; ++e) if (acc[t][e] > m1) { m1 = acc[t][e]; i1 = e; }
    float m2 = -1e30f; int i2 = 0;
#pragma unroll
    for (int e = 0; e < 8; ++e)
      if (e != i1 && acc[t][e] > m2) { m2 = acc[t][e]; i2 = e; }
    // renormalized top-2 softmax: w1 = p1/(p1+p2) = 1/(1+exp(l2-l1))
    float w1 = 1.f / (1.f + expf(m2 - m1));
    if (lane < 8) {
      float v = (lane == i1) ? w1 : (lane == i2) ? (1.f - w1) : 0.f;
      Comb[(size_t)(tok0 + t) * 8 + lane] = v * SCALING;
    }
  }
}

// ---------------- kernel 3: h = x_bf @ A_all^T, weighted -> hw_bf -------
// Tile 32(tokens) x 128(all E*r cols), K=4096. 4 waves: 2m x 2n of 16x64.
__global__ __launch_bounds__(256, 2) void h_gemm_kernel(
    const unsigned short* __restrict__ Xb, const unsigned short* __restrict__ Ab,
    const float* __restrict__ Comb, unsigned short* __restrict__ Hw) {
  __shared__ unsigned short As[32 * 32];    // 2 KB
  __shared__ unsigned short Bs[ER * 32];    // 8 KB
  int tid = threadIdx.x, wave = tid >> 6, lane = tid & 63;
  int row0 = blockIdx.x * 32;

  // A staging: 128 chunks of 16B; waves 0,1 issue one call each
  int chA = wave * 64 + lane;
  int rA = chA >> 2, kA = (chA & 3) * 8;
  const unsigned short* srcA = Xb + (size_t)(row0 + rA) * D_IN + kA;
  unsigned short* dstA = As + wave * 512;
  // B staging: 512 chunks; every wave 2 calls
  int chB0 = (wave * 2) * 64 + lane, chB1 = chB0 + 64;
  int rB0 = chB0 >> 2, kB0 = (chB0 & 3) * 8;
  int rB1 = chB1 >> 2, kB1 = (chB1 & 3) * 8;
  const unsigned short* srcB0 = Ab + (size_t)rB0 * D_IN + kB0;
  const unsigned short* srcB1 = Ab + (size_t)rB1 * D_IN + kB1;
  unsigned short* dstB0 = Bs + (wave * 2) * 512;
  unsigned short* dstB1 = Bs + (wave * 2 + 1) * 512;

  int wm = wave >> 1, wn = wave & 1;
  f32x4 acc[4];
#pragma unroll
  for (int ni = 0; ni < 4; ++ni) acc[ni] = (f32x4){0.f, 0.f, 0.f, 0.f};

  for (int kt = 0; kt < D_IN / 32; ++kt) {
    if (wave < 2) { gload_lds16(srcA, dstA); }
    srcA += 32;
    gload_lds16(srcB0, dstB0); srcB0 += 32;
    gload_lds16(srcB1, dstB1); srcB1 += 32;
    __syncthreads();
    short8 a = *(const short8*)&As[(wm * 16 + (lane & 15)) * 32 + (lane >> 4) * 8];
    short8 b[4];
#pragma unroll
    for (int ni = 0; ni < 4; ++ni)
      b[ni] = *(const short8*)&Bs[(wn * 64 + ni * 16 + (lane & 15)) * 32 + (lane >> 4) * 8];
#pragma unroll
    for (int ni = 0; ni < 4; ++ni)
      acc[ni] = __builtin_amdgcn_mfma_f32_16x16x32_bf16(a, b[ni], acc[ni], 0, 0, 0);
    __syncthreads();
  }
#pragma unroll
  for (int ni = 0; ni < 4; ++ni) {
    int c = wn * 64 + ni * 16 + (lane & 15);
    int e = c >> 4;
#pragma unroll
    for (int i = 0; i < 4; ++i) {
      int r = row0 + wm * 16 + (lane >> 4) * 4 + i;
      float v = acc[ni][i] * Comb[(size_t)r * 8 + e];
      Hw[(size_t)r * ER + c] = f2bf(v);
    }
  }
}

// ---------------- kernel 4: out = x_bf@Wb^T + bias + hw_bf@Bcb^T --------
// m97 structure: 128x128 tile, BK=32, 4 waves (2x2 of 64x64), K = 4096+128.
__global__ __launch_bounds__(256, 2) void main_gemm_kernel(
    const unsigned short* __restrict__ Xb, const unsigned short* __restrict__ Wb,
    const unsigned short* __restrict__ Hw, const unsigned short* __restrict__ Bcb,
    const float* __restrict__ bias, float* __restrict__ Out) {
  __shared__ unsigned short As[128 * 32];   // 8 KB
  __shared__ unsigned short Bs[128 * 32];   // 8 KB
  int tid = threadIdx.x, wave = tid >> 6, lane = tid & 63;
  int bid = blockIdx.x;
  // XCD-aware swizzle: 2048 blocks = 8 XCDs x 256 contiguous tiles
  int swz = (bid & 7) * 256 + (bid >> 3);
  int mb = swz >> 5, nb = swz & 31;
  int row0 = mb * 128, col0 = nb * 128;

  // staging geometry: 512 chunks of 16B per tile; 2 calls per wave per tile
  int cA0 = wave * 2, cA1 = wave * 2 + 1;
  int chA0 = cA0 * 64 + lane, chA1 = chA0 + 64;
  int rA0 = chA0 >> 2, kA0 = (chA0 & 3) * 8;
  int rA1 = chA1 >> 2, kA1 = (chA1 & 3) * 8;
  const unsigned short* srcA0 = Xb + (size_t)(row0 + rA0) * D_IN + kA0;
  const unsigned short* srcA1 = Xb + (size_t)(row0 + rA1) * D_IN + kA1;
  const unsigned short* srcB0 = Wb + (size_t)(col0 + rA0) * D_IN + kA0;
  const unsigned short* srcB1 = Wb + (size_t)(col0 + rA1) * D_IN + kA1;
  unsigned short* dstA0 = As + cA0 * 512;
  unsigned short* dstA1 = As + cA1 * 512;
  unsigned short* dstB0 = Bs + cA0 * 512;
  unsigned short* dstB1 = Bs + cA1 * 512;

  int wm = wave >> 1, wn = wave & 1;
  f32x4 acc[4][4];
#pragma unroll
  for (int mi = 0; mi < 4; ++mi)
#pragma unroll
    for (int ni = 0; ni < 4; ++ni) acc[mi][ni] = (f32x4){0.f, 0.f, 0.f, 0.f};

  // ---- K1: base weights, 4096/32 = 128 steps ----
  for (int kt = 0; kt < D_IN / 32; ++kt) {
    gload_lds16(srcA0, dstA0); srcA0 += 32;
    gload_lds16(srcA1, dstA1); srcA1 += 32;
    gload_lds16(srcB0, dstB0); srcB0 += 32;
    gload_lds16(srcB1, dstB1); srcB1 += 32;
    __syncthreads();
    short8 a[4], b[4];
#pragma unroll
    for (int mi = 0; mi < 4; ++mi)
      a[mi] = *(const short8*)&As[(wm * 64 + mi * 16 + (lane & 15)) * 32 + (lane >> 4) * 8];
#pragma unroll
    for (int ni = 0; ni < 4; ++ni)
      b[ni] = *(const short8*)&Bs[(wn * 64 + ni * 16 + (lane & 15)) * 32 + (lane >> 4) * 8];
#pragma unroll
    for (int mi = 0; mi < 4; ++mi)
#pragma unroll
      for (int ni = 0; ni < 4; ++ni)
        acc[mi][ni] = __builtin_amdgcn_mfma_f32_16x16x32_bf16(a[mi], b[ni], acc[mi][ni], 0, 0, 0);
    __syncthreads();
  }

  // ---- K2: lora low-rank part, 128/32 = 4 steps ----
  const unsigned short* sA0 = Hw + (size_t)(row0 + rA0) * ER + kA0;
  const unsigned short* sA1 = Hw + (size_t)(row0 + rA1) * ER + kA1;
  const unsigned short* sB0 = Bcb + (size_t)(col0 + rA0) * ER + kA0;
  const unsigned short* sB1 = Bcb + (size_t)(col0 + rA1) * ER + kA1;
  for (int kt = 0; kt < ER / 32; ++kt) {
    gload_lds16(sA0, dstA0); sA0 += 32;
    gload_lds16(sA1, dstA1); sA1 += 32;
    gload_lds16(sB0, dstB0); sB0 += 32;
    gload_lds16(sB1, dstB1); sB1 += 32;
    __syncthreads();
    short8 a[4], b[4];
#pragma unroll
    for (int mi = 0; mi < 4; ++mi)
      a[mi] = *(const short8*)&As[(wm * 64 + mi * 16 + (lane & 15)) * 32 + (lane >> 4) * 8];
#pragma unroll
    for (int ni = 0; ni < 4; ++ni)
      b[ni] = *(const short8*)&Bs[(wn * 64 + ni * 16 + (lane & 15)) * 32 + (lane >> 4) * 8];
#pragma unroll
    for (int mi = 0; mi < 4; ++mi)
#pragma unroll
      for (int ni = 0; ni < 4; ++ni)
        acc[mi][ni] = __builtin_amdgcn_mfma_f32_16x16x32_bf16(a[mi], b[ni], acc[mi][ni], 0, 0, 0);
    __syncthreads();
  }

  // ---- epilogue: bias add, f32 store ----
#pragma unroll
  for (int mi = 0; mi < 4; ++mi)
#pragma unroll
    for (int ni = 0; ni < 4; ++ni) {
      int c = col0 + wn * 64 + ni * 16 + (lane & 15);
      float bv = bias[c];
#pragma unroll
      for (int i = 0; i < 4; ++i) {
        int r = row0 + wm * 64 + mi * 16 + (lane >> 4) * 4 + i;
        Out[(size_t)r * D_OUT + c] = acc[mi][ni][i] + bv;
      }
    }
}

extern "C" void kernel_launch(void* const* d_in, const int* in_sizes, int n_in,
                              void* d_out, int out_size, void* d_ws, size_t ws_size,
                              hipStream_t stream) {
  const float* x        = (const float*)d_in[0];
  const float* W_base   = (const float*)d_in[1];
  const float* b_base   = (const float*)d_in[2];
  const float* W_router = (const float*)d_in[3];
  const float* A_stack  = (const float*)d_in[4];
  const float* B_stack  = (const float*)d_in[5];
  float* out = (float*)d_out;

  char* ws = (char*)d_ws;
  unsigned short* Xb  = (unsigned short*)(ws);                  // 67,108,864 B
  unsigned short* Wb  = (unsigned short*)(ws + 67108864);       // 33,554,432 B
  unsigned short* Ab  = (unsigned short*)(ws + 100663296);      //  1,048,576 B
  unsigned short* Bcb = (unsigned short*)(ws + 101711872);      //  1,048,576 B
  unsigned short* Hw  = (unsigned short*)(ws + 102760448);      //  2,097,152 B
  float*          Comb = (float*)(ws + 104857600);              //    262,144 B
  // total ws use: ~105 MB

  hipLaunchKernelGGL(prep_kernel, dim3(2048), dim3(256), 0, stream,
                     W_base, A_stack, B_stack, Wb, Ab, Bcb);
  hipLaunchKernelGGL(router_kernel, dim3(512), dim3(256), 0, stream,
                     x, W_router, Xb, Comb);
  hipLaunchKernelGGL(h_gemm_kernel, dim3(256), dim3(256), 0, stream,
                     Xb, Ab, Comb, Hw);
  hipLaunchKernelGGL(main_gemm_kernel, dim3(2048), dim3(256), 0, stream,
                     Xb, Wb, Hw, Bcb, b_base, out);
}

// Round 2
// 387.363 us; speedup vs baseline: 1.1817x; 1.1817x over previous
//
#include <hip/hip_runtime.h>

#define D_IN   4096
#define D_OUT  4096
#define N_TOK  8192
#define RANK   16
#define NEXP   8
#define ER     128          // NEXP*RANK — lora inner width
#define SCALING 2.0f        // 32/16

typedef __attribute__((ext_vector_type(8))) short short8;     // 8 bf16 (4 VGPR)
typedef __attribute__((ext_vector_type(4))) float f32x4;
typedef __attribute__((ext_vector_type(4))) unsigned short us4;
typedef unsigned int uint;

__device__ __forceinline__ unsigned short f2bf(float f) {
  unsigned u = __float_as_uint(f);
  u += 0x7FFFu + ((u >> 16) & 1u);     // RNE
  return (unsigned short)(u >> 16);
}

__device__ __forceinline__ void gload_lds16(const void* g, void* l) {
  __builtin_amdgcn_global_load_lds(
      (const __attribute__((address_space(1))) unsigned int*)g,
      (__attribute__((address_space(3))) unsigned int*)l, 16, 0, 0);
}

// ---------------- kernel 1: weight conversions --------------------------
__global__ void prep_kernel(const float* __restrict__ W, const float* __restrict__ A,
                            const float* __restrict__ B,
                            unsigned short* __restrict__ Wb,
                            unsigned short* __restrict__ Ab,
                            unsigned short* __restrict__ Bcb) {
  const int NW4 = (D_OUT * D_IN) / 4;     // 4194304
  const int NA4 = (ER * D_IN) / 4;        // 131072
  const int NB4 = (D_OUT * ER) / 4;       // 131072
  const int total = NW4 + NA4 + NB4;
  for (int i = blockIdx.x * blockDim.x + threadIdx.x; i < total;
       i += gridDim.x * blockDim.x) {
    if (i < NW4) {
      float4 v = ((const float4*)W)[i];
      us4 o = { f2bf(v.x), f2bf(v.y), f2bf(v.z), f2bf(v.w) };
      ((us4*)Wb)[i] = o;
    } else if (i < NW4 + NA4) {
      int j = i - NW4;
      float4 v = ((const float4*)A)[j];
      us4 o = { f2bf(v.x), f2bf(v.y), f2bf(v.z), f2bf(v.w) };
      ((us4*)Ab)[j] = o;
    } else {
      int j = i - NW4 - NA4;              // out float4 idx = o*32 + e*4 + rq
      int o = j >> 5; int rem = j & 31; int e = rem >> 2; int rq = rem & 3;
      float4 v = *(const float4*)(B + (size_t)e * D_OUT * RANK + o * RANK + rq * 4);
      us4 ob = { f2bf(v.x), f2bf(v.y), f2bf(v.z), f2bf(v.w) };
      ((us4*)Bcb)[j] = ob;
    }
  }
}

// ---------------- kernel 2: x->bf16 + f32 router + top-2 combine --------
__global__ __launch_bounds__(256) void router_kernel(
    const float* __restrict__ X, const float* __restrict__ Wr,
    unsigned short* __restrict__ Xb, float* __restrict__ Comb) {
  int wave = threadIdx.x >> 6, lane = threadIdx.x & 63;
  int tok0 = blockIdx.x * 16 + wave * 4;
  float acc[4][8];
#pragma unroll
  for (int t = 0; t < 4; ++t)
#pragma unroll
    for (int e = 0; e < 8; ++e) acc[t][e] = 0.f;
  const float4* X4 = (const float4*)X;
  const float4* W4 = (const float4*)Wr;
#pragma unroll 1
  for (int it = 0; it < 16; ++it) {
    int kq = it * 64 + lane;
    float4 w[8];
#pragma unroll
    for (int e = 0; e < 8; ++e) w[e] = W4[e * 1024 + kq];
#pragma unroll
    for (int t = 0; t < 4; ++t) {
      float4 xv = X4[(size_t)(tok0 + t) * 1024 + kq];
      us4 xb = { f2bf(xv.x), f2bf(xv.y), f2bf(xv.z), f2bf(xv.w) };
      ((us4*)Xb)[(size_t)(tok0 + t) * 1024 + kq] = xb;
#pragma unroll
      for (int e = 0; e < 8; ++e)
        acc[t][e] = fmaf(xv.x, w[e].x, fmaf(xv.y, w[e].y,
                     fmaf(xv.z, w[e].z, fmaf(xv.w, w[e].w, acc[t][e]))));
    }
  }
#pragma unroll
  for (int t = 0; t < 4; ++t)
#pragma unroll
    for (int e = 0; e < 8; ++e) {
      float v = acc[t][e];
      for (int off = 32; off; off >>= 1) v += __shfl_xor(v, off, 64);
      acc[t][e] = v;
    }
#pragma unroll
  for (int t = 0; t < 4; ++t) {
    float m1 = acc[t][0]; int i1 = 0;
#pragma unroll
    for (int e = 1; e < 8; ++e) if (acc[t][e] > m1) { m1 = acc[t][e]; i1 = e; }
    float m2 = -1e30f; int i2 = 0;
#pragma unroll
    for (int e = 0; e < 8; ++e)
      if (e != i1 && acc[t][e] > m2) { m2 = acc[t][e]; i2 = e; }
    float w1 = 1.f / (1.f + expf(m2 - m1));
    if (lane < 8) {
      float v = (lane == i1) ? w1 : (lane == i2) ? (1.f - w1) : 0.f;
      Comb[(size_t)(tok0 + t) * 8 + lane] = v * SCALING;
    }
  }
}

// ---------------- kernel 3: h = x_bf @ A_all^T, weighted -> hw_bf -------
__global__ __launch_bounds__(256, 2) void h_gemm_kernel(
    const unsigned short* __restrict__ Xb, const unsigned short* __restrict__ Ab,
    const float* __restrict__ Comb, unsigned short* __restrict__ Hw) {
  __shared__ unsigned short As[32 * 32];
  __shared__ unsigned short Bs[ER * 32];
  int tid = threadIdx.x, wave = tid >> 6, lane = tid & 63;
  int row0 = blockIdx.x * 32;

  int chA = wave * 64 + lane;
  int rA = chA >> 2, kA = (chA & 3) * 8;
  const unsigned short* srcA = Xb + (size_t)(row0 + rA) * D_IN + kA;
  unsigned short* dstA = As + wave * 512;
  int chB0 = (wave * 2) * 64 + lane, chB1 = chB0 + 64;
  int rB0 = chB0 >> 2, kB0 = (chB0 & 3) * 8;
  int rB1 = chB1 >> 2, kB1 = (chB1 & 3) * 8;
  const unsigned short* srcB0 = Ab + (size_t)rB0 * D_IN + kB0;
  const unsigned short* srcB1 = Ab + (size_t)rB1 * D_IN + kB1;
  unsigned short* dstB0 = Bs + (wave * 2) * 512;
  unsigned short* dstB1 = Bs + (wave * 2 + 1) * 512;

  int wm = wave >> 1, wn = wave & 1;
  f32x4 acc[4];
#pragma unroll
  for (int ni = 0; ni < 4; ++ni) acc[ni] = (f32x4){0.f, 0.f, 0.f, 0.f};

  for (int kt = 0; kt < D_IN / 32; ++kt) {
    if (wave < 2) { gload_lds16(srcA, dstA); }
    srcA += 32;
    gload_lds16(srcB0, dstB0); srcB0 += 32;
    gload_lds16(srcB1, dstB1); srcB1 += 32;
    __syncthreads();
    short8 a = *(const short8*)&As[(wm * 16 + (lane & 15)) * 32 + (lane >> 4) * 8];
    short8 b[4];
#pragma unroll
    for (int ni = 0; ni < 4; ++ni)
      b[ni] = *(const short8*)&Bs[(wn * 64 + ni * 16 + (lane & 15)) * 32 + (lane >> 4) * 8];
#pragma unroll
    for (int ni = 0; ni < 4; ++ni)
      acc[ni] = __builtin_amdgcn_mfma_f32_16x16x32_bf16(a, b[ni], acc[ni], 0, 0, 0);
    __syncthreads();
  }
#pragma unroll
  for (int ni = 0; ni < 4; ++ni) {
    int c = wn * 64 + ni * 16 + (lane & 15);
    int e = c >> 4;
#pragma unroll
    for (int i = 0; i < 4; ++i) {
      int r = row0 + wm * 16 + (lane >> 4) * 4 + i;
      float v = acc[ni][i] * Comb[(size_t)r * 8 + e];
      Hw[(size_t)r * ER + c] = f2bf(v);
    }
  }
}

// ---------------- kernel 4: 256x256 tile, BK=32, 4-slot LDS ring --------
// out = x_bf@Wb^T + bias + hw_bf@Bcb^T.  K = 4224 = 132 tiles of 32.
// 8 waves (2M x 4N), per-wave C = 128x64 (8x4 frags). Prefetch depth 3,
// counted vmcnt(8) once per K-tile. XOR-swizzled LDS (slot ^= (row>>1)&3).
__global__ __launch_bounds__(512, 2) void main_gemm_kernel(
    const unsigned short* __restrict__ Xb, const unsigned short* __restrict__ Wb,
    const unsigned short* __restrict__ Hw, const unsigned short* __restrict__ Bcb,
    const float* __restrict__ bias, float* __restrict__ Out) {
  __shared__ unsigned short lds[4 * 16384];   // 128 KB: 4 slots x (A 16KB | B 16KB)
  char* ldsc = (char*)lds;
  const int tid = threadIdx.x;
  const int wave = tid >> 6, lane = tid & 63;
  const int wm = wave >> 2, wn = wave & 3;     // 2 x 4 wave grid
  const int ks = lane >> 4;

  int bid = blockIdx.x;
  int swz = (bid & 7) * 64 + (bid >> 3);       // 512 blocks, 8 XCDs, bijective
  int mb = swz >> 4, nb = swz & 15;            // 32 x 16 tiles
  const int row0 = mb * 256, col0 = nb * 256;

  // staging source offsets (pre-swizzled global, linear LDS dest)
  uint offX[2], offH[2], offW[2], offC[2], dstA[2], dstB[2];
#pragma unroll
  for (int c = 0; c < 2; ++c) {
    int ch = c * 512 + tid;
    int rr = ch >> 2;
    int ss = (ch & 3) ^ ((ch >> 3) & 3);       // inverse st-swizzle on source
    offX[c] = (uint)(row0 + rr) * D_IN + ss * 8;
    offH[c] = (uint)(row0 + rr) * ER + ss * 8;
    offW[c] = (uint)(col0 + rr) * D_IN + ss * 8;
    offC[c] = (uint)(col0 + rr) * ER + ss * 8;
    dstA[c] = c * 8192 + wave * 1024;          // wave-uniform linear dest
    dstB[c] = 16384 + c * 8192 + wave * 1024;
  }

  // ds_read offsets (swizzled): byte = r*64 + (ks ^ ((r>>1)&3))*16
  uint offA[8], offB[4];
#pragma unroll
  for (int mi = 0; mi < 8; ++mi) {
    int r = wm * 128 + mi * 16 + (lane & 15);
    offA[mi] = (uint)r * 64 + (uint)((ks ^ ((r >> 1) & 3)) * 16);
  }
#pragma unroll
  for (int ni = 0; ni < 4; ++ni) {
    int r = wn * 64 + ni * 16 + (lane & 15);
    offB[ni] = 16384u + (uint)r * 64 + (uint)((ks ^ ((r >> 1) & 3)) * 16);
  }

  auto stageA = [&](int t) {
    uint sb_ = (uint)(t & 3) * 32768u;
    const unsigned short *s0, *s1;
    if (t < 128) { s0 = Xb + offX[0] + t * 32; s1 = Xb + offX[1] + t * 32; }
    else         { s0 = Hw + offH[0] + (t - 128) * 32; s1 = Hw + offH[1] + (t - 128) * 32; }
    gload_lds16(s0, ldsc + sb_ + dstA[0]);
    gload_lds16(s1, ldsc + sb_ + dstA[1]);
  };
  auto stageB = [&](int t) {
    uint sb_ = (uint)(t & 3) * 32768u;
    const unsigned short *s0, *s1;
    if (t < 128) { s0 = Wb + offW[0] + t * 32; s1 = Wb + offW[1] + t * 32; }
    else         { s0 = Bcb + offC[0] + (t - 128) * 32; s1 = Bcb + offC[1] + (t - 128) * 32; }
    gload_lds16(s0, ldsc + sb_ + dstB[0]);
    gload_lds16(s1, ldsc + sb_ + dstB[1]);
  };

  f32x4 acc[8][4];
#pragma unroll
  for (int mi = 0; mi < 8; ++mi)
#pragma unroll
    for (int ni = 0; ni < 4; ++ni) acc[mi][ni] = (f32x4){0.f, 0.f, 0.f, 0.f};

  // prologue: stage tiles 0,1,2 (12 loads/wave); wait tile 0 (leave 8 in flight)
  stageA(0); stageB(0); stageA(1); stageB(1); stageA(2); stageB(2);
  asm volatile("s_waitcnt vmcnt(8)" ::: );
  __builtin_amdgcn_s_barrier();
  __builtin_amdgcn_sched_barrier(0);

#pragma unroll 1
  for (int i4 = 0; i4 < 33; ++i4) {
#pragma unroll
    for (int j = 0; j < 4; ++j) {
      const int i = i4 * 4 + j;
      const uint sb = (uint)j * 32768u;        // slot = i & 3 == j
      const int t3 = i + 3;
      // ---- phase 0: frags (A quad 0 + all B) | stage matrix-A of t3 ----
      short8 a0[4], bf[4];
#pragma unroll
      for (int m = 0; m < 4; ++m) a0[m] = *(const short8*)(ldsc + sb + offA[m]);
#pragma unroll
      for (int n = 0; n < 4; ++n) bf[n] = *(const short8*)(ldsc + sb + offB[n]);
      if (t3 <= 131) stageA(t3);
      __builtin_amdgcn_sched_barrier(0);
      __builtin_amdgcn_s_barrier();
      __builtin_amdgcn_sched_barrier(0);
      __builtin_amdgcn_s_setprio(1);
#pragma unroll
      for (int m = 0; m < 4; ++m)
#pragma unroll
        for (int n = 0; n < 4; ++n)
          acc[m][n] = __builtin_amdgcn_mfma_f32_16x16x32_bf16(a0[m], bf[n], acc[m][n], 0, 0, 0);
      __builtin_amdgcn_s_setprio(0);
      __builtin_amdgcn_sched_barrier(0);
      __builtin_amdgcn_s_barrier();
      __builtin_amdgcn_sched_barrier(0);
      // ---- phase 1: frags (A quad 1, reuse B regs) | stage matrix-B of t3 ----
      short8 a1[4];
#pragma unroll
      for (int m = 0; m < 4; ++m) a1[m] = *(const short8*)(ldsc + sb + offA[4 + m]);
      if (t3 <= 131) stageB(t3);
      __builtin_amdgcn_sched_barrier(0);
      __builtin_amdgcn_s_barrier();
      __builtin_amdgcn_sched_barrier(0);
      __builtin_amdgcn_s_setprio(1);
#pragma unroll
      for (int m = 0; m < 4; ++m)
#pragma unroll
        for (int n = 0; n < 4; ++n)
          acc[4 + m][n] = __builtin_amdgcn_mfma_f32_16x16x32_bf16(a1[m], bf[n], acc[4 + m][n], 0, 0, 0);
      __builtin_amdgcn_s_setprio(0);
      __builtin_amdgcn_sched_barrier(0);
      // counted vmcnt: tile i+1 landed; tiles i+2, i+3 (8 loads) stay in flight
      if (i <= 128)      { asm volatile("s_waitcnt vmcnt(8)" ::: ); }
      else if (i == 129) { asm volatile("s_waitcnt vmcnt(4)" ::: ); }
      else if (i == 130) { asm volatile("s_waitcnt vmcnt(0)" ::: ); }
      __builtin_amdgcn_s_barrier();
      __builtin_amdgcn_sched_barrier(0);
    }
  }

  // ---- epilogue: bias add, f32 store ----
#pragma unroll
  for (int ni = 0; ni < 4; ++ni) {
    const int c = col0 + wn * 64 + ni * 16 + (lane & 15);
    const float bv = bias[c];
#pragma unroll
    for (int mi = 0; mi < 8; ++mi) {
#pragma unroll
      for (int i = 0; i < 4; ++i) {
        int r = row0 + wm * 128 + mi * 16 + ks * 4 + i;
        Out[(size_t)r * D_OUT + c] = acc[mi][ni][i] + bv;
      }
    }
  }
}

extern "C" void kernel_launch(void* const* d_in, const int* in_sizes, int n_in,
                              void* d_out, int out_size, void* d_ws, size_t ws_size,
                              hipStream_t stream) {
  const float* x        = (const float*)d_in[0];
  const float* W_base   = (const float*)d_in[1];
  const float* b_base   = (const float*)d_in[2];
  const float* W_router = (const float*)d_in[3];
  const float* A_stack  = (const float*)d_in[4];
  const float* B_stack  = (const float*)d_in[5];
  float* out = (float*)d_out;

  char* ws = (char*)d_ws;
  unsigned short* Xb  = (unsigned short*)(ws);                  // 67,108,864 B
  unsigned short* Wb  = (unsigned short*)(ws + 67108864);       // 33,554,432 B
  unsigned short* Ab  = (unsigned short*)(ws + 100663296);      //  1,048,576 B
  unsigned short* Bcb = (unsigned short*)(ws + 101711872);      //  1,048,576 B
  unsigned short* Hw  = (unsigned short*)(ws + 102760448);      //  2,097,152 B
  float*          Comb = (float*)(ws + 104857600);              //    262,144 B

  hipLaunchKernelGGL(prep_kernel, dim3(2048), dim3(256), 0, stream,
                     W_base, A_stack, B_stack, Wb, Ab, Bcb);
  hipLaunchKernelGGL(router_kernel, dim3(512), dim3(256), 0, stream,
                     x, W_router, Xb, Comb);
  hipLaunchKernelGGL(h_gemm_kernel, dim3(256), dim3(256), 0, stream,
                     Xb, Ab, Comb, Hw);
  hipLaunchKernelGGL(main_gemm_kernel, dim3(512), dim3(512), 0, stream,
                     Xb, Wb, Hw, Bcb, b_base, out);
}

// Round 3
// 335.498 us; speedup vs baseline: 1.3644x; 1.1546x over previous
//
#include <hip/hip_runtime.h>

#define D_IN   4096
#define D_OUT  4096
#define N_TOK  8192
#define RANK   16
#define NEXP   8
#define ER     128          // NEXP*RANK — lora inner width
#define KCAT   4224         // D_IN + ER — concatenated K
#define SCALING 2.0f        // 32/16

typedef __attribute__((ext_vector_type(8))) short short8;     // 8 bf16 (4 VGPR)
typedef __attribute__((ext_vector_type(4))) float f32x4;
typedef __attribute__((ext_vector_type(4))) unsigned short us4;
typedef unsigned int uint;

__device__ __forceinline__ unsigned short f2bf(float f) {
  unsigned u = __float_as_uint(f);
  u += 0x7FFFu + ((u >> 16) & 1u);     // RNE
  return (unsigned short)(u >> 16);
}

__device__ __forceinline__ void gload_lds16(const void* g, void* l) {
  __builtin_amdgcn_global_load_lds(
      (const __attribute__((address_space(1))) unsigned int*)g,
      (__attribute__((address_space(3))) unsigned int*)l, 16, 0, 0);
}

// ---------------- kernel 1: weight conversions --------------------------
// Wcat[o][0..4095] = bf16(W_base[o][k]); Wcat[o][4096 + e*16 + r] = bf16(B_stack[e][o][r])
// Ab[e*16+r][k] = bf16(A_stack[e][r][k]) (linear copy)
__global__ void prep_kernel(const float* __restrict__ W, const float* __restrict__ A,
                            const float* __restrict__ B,
                            unsigned short* __restrict__ Wcat,
                            unsigned short* __restrict__ Ab) {
  const int NW4 = (D_OUT * D_IN) / 4;     // 4194304
  const int NA4 = (ER * D_IN) / 4;        // 131072
  const int NB4 = (D_OUT * ER) / 4;       // 131072
  const int total = NW4 + NA4 + NB4;
  for (int i = blockIdx.x * blockDim.x + threadIdx.x; i < total;
       i += gridDim.x * blockDim.x) {
    if (i < NW4) {
      float4 v = ((const float4*)W)[i];
      us4 o = { f2bf(v.x), f2bf(v.y), f2bf(v.z), f2bf(v.w) };
      int row = i >> 10, kq = i & 1023;
      ((us4*)(Wcat + (size_t)row * KCAT))[kq] = o;
    } else if (i < NW4 + NA4) {
      int j = i - NW4;
      float4 v = ((const float4*)A)[j];
      us4 o = { f2bf(v.x), f2bf(v.y), f2bf(v.z), f2bf(v.w) };
      ((us4*)Ab)[j] = o;
    } else {
      int j = i - NW4 - NA4;              // float4 idx = o*32 + e*4 + rq
      int o = j >> 5; int rem = j & 31; int e = rem >> 2; int rq = rem & 3;
      float4 v = *(const float4*)(B + (size_t)e * D_OUT * RANK + o * RANK + rq * 4);
      us4 ob = { f2bf(v.x), f2bf(v.y), f2bf(v.z), f2bf(v.w) };
      *(us4*)(Wcat + (size_t)o * KCAT + D_IN + e * 16 + rq * 4) = ob;
    }
  }
}

// ---------------- kernel 2: x->bf16 (into Xcat) + f32 router + top-2 ----
__global__ __launch_bounds__(256) void router_kernel(
    const float* __restrict__ X, const float* __restrict__ Wr,
    unsigned short* __restrict__ Xcat, float* __restrict__ Comb) {
  int wave = threadIdx.x >> 6, lane = threadIdx.x & 63;
  int tok0 = blockIdx.x * 16 + wave * 4;
  float acc[4][8];
#pragma unroll
  for (int t = 0; t < 4; ++t)
#pragma unroll
    for (int e = 0; e < 8; ++e) acc[t][e] = 0.f;
  const float4* X4 = (const float4*)X;
  const float4* W4 = (const float4*)Wr;
#pragma unroll 1
  for (int it = 0; it < 16; ++it) {
    int kq = it * 64 + lane;
    float4 w[8];
#pragma unroll
    for (int e = 0; e < 8; ++e) w[e] = W4[e * 1024 + kq];
#pragma unroll
    for (int t = 0; t < 4; ++t) {
      float4 xv = X4[(size_t)(tok0 + t) * 1024 + kq];
      us4 xb = { f2bf(xv.x), f2bf(xv.y), f2bf(xv.z), f2bf(xv.w) };
      ((us4*)(Xcat + (size_t)(tok0 + t) * KCAT))[kq] = xb;
#pragma unroll
      for (int e = 0; e < 8; ++e)
        acc[t][e] = fmaf(xv.x, w[e].x, fmaf(xv.y, w[e].y,
                     fmaf(xv.z, w[e].z, fmaf(xv.w, w[e].w, acc[t][e]))));
    }
  }
#pragma unroll
  for (int t = 0; t < 4; ++t)
#pragma unroll
    for (int e = 0; e < 8; ++e) {
      float v = acc[t][e];
      for (int off = 32; off; off >>= 1) v += __shfl_xor(v, off, 64);
      acc[t][e] = v;
    }
#pragma unroll
  for (int t = 0; t < 4; ++t) {
    float m1 = acc[t][0]; int i1 = 0;
#pragma unroll
    for (int e = 1; e < 8; ++e) if (acc[t][e] > m1) { m1 = acc[t][e]; i1 = e; }
    float m2 = -1e30f; int i2 = 0;
#pragma unroll
    for (int e = 0; e < 8; ++e)
      if (e != i1 && acc[t][e] > m2) { m2 = acc[t][e]; i2 = e; }
    float w1 = 1.f / (1.f + expf(m2 - m1));
    if (lane < 8) {
      float v = (lane == i1) ? w1 : (lane == i2) ? (1.f - w1) : 0.f;
      Comb[(size_t)(tok0 + t) * 8 + lane] = v * SCALING;
    }
  }
}

// ---------------- kernel 3: h = x_bf @ A_all^T, weighted -> Xcat[:,4096+] ---
// 256 blocks x 32 tokens. BK=128, 3-slot LDS ring (A 8KB + B 32KB per slot),
// counted vmcnt(10). 4 waves (2x2), per-wave 16x64 output.
#define HSTG(S) { const uint hbase = (S) * 40960u; \
  _Pragma("unroll") for (int c = 0; c < 2; ++c) { gload_lds16(pa[c], ldsc + hbase + da[c]); pa[c] += 128; } \
  _Pragma("unroll") for (int c = 0; c < 8; ++c) { gload_lds16(pb[c], ldsc + hbase + db[c]); pb[c] += 128; } }

#define HTILE(S, S2, DOSTG, VM) { const uint hb = (S) * 40960u; \
  short8 af[4]; short8 bfr[4][4]; \
  _Pragma("unroll") for (int kk = 0; kk < 4; ++kk) af[kk] = *(const short8*)(ldsc + hb + oA[kk]); \
  _Pragma("unroll") for (int n = 0; n < 4; ++n) \
    _Pragma("unroll") for (int kk = 0; kk < 4; ++kk) bfr[n][kk] = *(const short8*)(ldsc + hb + oB[n][kk]); \
  if (DOSTG) HSTG(S2); \
  __builtin_amdgcn_sched_barrier(0); __builtin_amdgcn_s_barrier(); __builtin_amdgcn_sched_barrier(0); \
  __builtin_amdgcn_s_setprio(1); \
  _Pragma("unroll") for (int kk = 0; kk < 4; ++kk) \
    _Pragma("unroll") for (int n = 0; n < 4; ++n) \
      acc[n] = __builtin_amdgcn_mfma_f32_16x16x32_bf16(af[kk], bfr[n][kk], acc[n], 0, 0, 0); \
  __builtin_amdgcn_s_setprio(0); \
  __builtin_amdgcn_sched_barrier(0); \
  asm volatile("s_waitcnt vmcnt(" #VM ")" ::: ); \
  __builtin_amdgcn_s_barrier(); __builtin_amdgcn_sched_barrier(0); }

__global__ __launch_bounds__(256, 1) void h_gemm_kernel(
    unsigned short* Xcat, const unsigned short* __restrict__ Ab,
    const float* __restrict__ Comb) {
  __shared__ unsigned short hlds[61440];     // 3 x 40960 B
  char* ldsc = (char*)hlds;
  const int tid = threadIdx.x, wave = tid >> 6, lane = tid & 63;
  const int wm = wave >> 1, wn = wave & 1;
  const int row0 = blockIdx.x * 32;

  // staging: A tile 32x128 (512 chunks, 2/thread), B tile 128x128 (2048 chunks, 8/thread)
  const unsigned short* pa[2]; uint da[2];
#pragma unroll
  for (int c = 0; c < 2; ++c) {
    int ch = c * 256 + tid, row = ch >> 4, s = ch & 15;
    pa[c] = Xcat + (size_t)(row0 + row) * KCAT + (s ^ ((row >> 1) & 7)) * 8;
    da[c] = (uint)ch * 16;
  }
  const unsigned short* pb[8]; uint db[8];
#pragma unroll
  for (int c = 0; c < 8; ++c) {
    int ch = c * 256 + tid, row = ch >> 4, s = ch & 15;
    pb[c] = Ab + (size_t)row * D_IN + (s ^ ((row >> 1) & 7)) * 8;
    db[c] = 8192u + (uint)ch * 16;
  }

  // frag read offsets (swizzled): byte = r*256 + (slot ^ ((r>>1)&7))*16, slot = kk*4 + (lane>>4)
  uint oA[4], oB[4][4];
  {
    int rA = wm * 16 + (lane & 15);
#pragma unroll
    for (int kk = 0; kk < 4; ++kk) {
      int slot = kk * 4 + (lane >> 4);
      oA[kk] = (uint)rA * 256 + (uint)((slot ^ ((rA >> 1) & 7)) * 16);
    }
#pragma unroll
    for (int n = 0; n < 4; ++n) {
      int rB = wn * 64 + n * 16 + (lane & 15);
#pragma unroll
      for (int kk = 0; kk < 4; ++kk) {
        int slot = kk * 4 + (lane >> 4);
        oB[n][kk] = 8192u + (uint)rB * 256 + (uint)((slot ^ ((rB >> 1) & 7)) * 16);
      }
    }
  }

  f32x4 acc[4];
#pragma unroll
  for (int n = 0; n < 4; ++n) acc[n] = (f32x4){0.f, 0.f, 0.f, 0.f};

  // prologue: stage tiles 0,1; wait tile 0
  HSTG(0); HSTG(1);
  asm volatile("s_waitcnt vmcnt(10)" ::: );
  __builtin_amdgcn_s_barrier();
  __builtin_amdgcn_sched_barrier(0);

#pragma unroll 1
  for (int i3 = 0; i3 < 10; ++i3) {        // tiles 0..29
    HTILE(0, 2, 1, 10);
    HTILE(1, 0, 1, 10);
    HTILE(2, 1, 1, 10);
  }
  HTILE(0, 0, 0, 0);                        // tile 30 (drain tile 31's loads)
  HTILE(1, 0, 0, 0);                        // tile 31

  // epilogue: weight by combine, write bf16 into Xcat cols 4096+
#pragma unroll
  for (int n = 0; n < 4; ++n) {
    int c = wn * 64 + n * 16 + (lane & 15);
    int e = c >> 4;
#pragma unroll
    for (int i = 0; i < 4; ++i) {
      int r = row0 + wm * 16 + (lane >> 4) * 4 + i;
      float v = acc[n][i] * Comb[(size_t)r * 8 + e];
      Xcat[(size_t)r * KCAT + D_IN + c] = f2bf(v);
    }
  }
}

// ---------------- kernel 4: out = Xcat @ Wcat^T + bias ------------------
// 256x256 tile, BK=32, K=4224 (132 tiles), 4-slot ring, branch-free staging.
#define STG_A(S) { gload_lds16(pA0, ldsc + (S) * 32768u + dA0); pA0 += 32; \
                   gload_lds16(pA1, ldsc + (S) * 32768u + dA1); pA1 += 32; }
#define STG_B(S) { gload_lds16(pB0, ldsc + (S) * 32768u + dB0); pB0 += 32; \
                   gload_lds16(pB1, ldsc + (S) * 32768u + dB1); pB1 += 32; }

#define MTILE(SLOT, SLOT3, DOSTG, VM) { \
  const uint sb = (SLOT) * 32768u; \
  short8 a0[4], bf[4], a1[4]; \
  _Pragma("unroll") for (int m = 0; m < 4; ++m) a0[m] = *(const short8*)(ldsc + sb + offA[m]); \
  _Pragma("unroll") for (int n = 0; n < 4; ++n) bf[n] = *(const short8*)(ldsc + sb + offB[n]); \
  if (DOSTG) STG_A(SLOT3); \
  __builtin_amdgcn_sched_barrier(0); __builtin_amdgcn_s_barrier(); __builtin_amdgcn_sched_barrier(0); \
  __builtin_amdgcn_s_setprio(1); \
  _Pragma("unroll") for (int m = 0; m < 4; ++m) \
    _Pragma("unroll") for (int n = 0; n < 4; ++n) \
      acc[m][n] = __builtin_amdgcn_mfma_f32_16x16x32_bf16(a0[m], bf[n], acc[m][n], 0, 0, 0); \
  __builtin_amdgcn_s_setprio(0); \
  __builtin_amdgcn_sched_barrier(0); __builtin_amdgcn_s_barrier(); __builtin_amdgcn_sched_barrier(0); \
  _Pragma("unroll") for (int m = 0; m < 4; ++m) a1[m] = *(const short8*)(ldsc + sb + offA[4 + m]); \
  if (DOSTG) STG_B(SLOT3); \
  __builtin_amdgcn_sched_barrier(0); __builtin_amdgcn_s_barrier(); __builtin_amdgcn_sched_barrier(0); \
  __builtin_amdgcn_s_setprio(1); \
  _Pragma("unroll") for (int m = 0; m < 4; ++m) \
    _Pragma("unroll") for (int n = 0; n < 4; ++n) \
      acc[4 + m][n] = __builtin_amdgcn_mfma_f32_16x16x32_bf16(a1[m], bf[n], acc[4 + m][n], 0, 0, 0); \
  __builtin_amdgcn_s_setprio(0); \
  __builtin_amdgcn_sched_barrier(0); \
  asm volatile("s_waitcnt vmcnt(" #VM ")" ::: ); \
  __builtin_amdgcn_s_barrier(); __builtin_amdgcn_sched_barrier(0); }

__global__ __launch_bounds__(512, 2) void main_gemm_kernel(
    const unsigned short* __restrict__ Xcat, const unsigned short* __restrict__ Wcat,
    const float* __restrict__ bias, float* __restrict__ Out) {
  __shared__ unsigned short lds[4 * 16384];   // 128 KB: 4 slots x (A 16KB | B 16KB)
  char* ldsc = (char*)lds;
  const int tid = threadIdx.x;
  const int wave = tid >> 6, lane = tid & 63;
  const int wm = wave >> 2, wn = wave & 3;     // 2 x 4 wave grid
  const int ks = lane >> 4;

  int bid = blockIdx.x;
  int swz = (bid & 7) * 64 + (bid >> 3);       // 512 blocks, 8 XCDs, bijective
  int mb = swz >> 4, nb = swz & 15;            // 32 x 16 tiles
  const int row0 = mb * 256, col0 = nb * 256;

  // staging: 1024 chunks of 16B per matrix-tile; 2 per thread. Pre-swizzled source.
  const unsigned short *pA0, *pA1, *pB0, *pB1;
  uint dA0, dA1, dB0, dB1;
  {
    int ch0 = tid, ch1 = 512 + tid;
    int rr0 = ch0 >> 2, ss0 = (ch0 & 3) ^ ((ch0 >> 3) & 3);
    int rr1 = ch1 >> 2, ss1 = (ch1 & 3) ^ ((ch1 >> 3) & 3);
    pA0 = Xcat + (size_t)(row0 + rr0) * KCAT + ss0 * 8;
    pA1 = Xcat + (size_t)(row0 + rr1) * KCAT + ss1 * 8;
    pB0 = Wcat + (size_t)(col0 + rr0) * KCAT + ss0 * 8;
    pB1 = Wcat + (size_t)(col0 + rr1) * KCAT + ss1 * 8;
    dA0 = (uint)wave * 1024;          dA1 = 8192u + (uint)wave * 1024;
    dB0 = 16384u + (uint)wave * 1024; dB1 = 24576u + (uint)wave * 1024;
  }

  // ds_read offsets (swizzled): byte = r*64 + (ks ^ ((r>>1)&3))*16
  uint offA[8], offB[4];
#pragma unroll
  for (int mi = 0; mi < 8; ++mi) {
    int r = wm * 128 + mi * 16 + (lane & 15);
    offA[mi] = (uint)r * 64 + (uint)((ks ^ ((r >> 1) & 3)) * 16);
  }
#pragma unroll
  for (int ni = 0; ni < 4; ++ni) {
    int r = wn * 64 + ni * 16 + (lane & 15);
    offB[ni] = 16384u + (uint)r * 64 + (uint)((ks ^ ((r >> 1) & 3)) * 16);
  }

  f32x4 acc[8][4];
#pragma unroll
  for (int mi = 0; mi < 8; ++mi)
#pragma unroll
    for (int ni = 0; ni < 4; ++ni) acc[mi][ni] = (f32x4){0.f, 0.f, 0.f, 0.f};

  // prologue: stage tiles 0,1,2 into slots 0,1,2; wait tile 0 (8 stay in flight)
  STG_A(0); STG_B(0); STG_A(1); STG_B(1); STG_A(2); STG_B(2);
  asm volatile("s_waitcnt vmcnt(8)" ::: );
  __builtin_amdgcn_s_barrier();
  __builtin_amdgcn_sched_barrier(0);

#pragma unroll 1
  for (int i4 = 0; i4 < 32; ++i4) {            // tiles 0..127, stage 3..130
    MTILE(0, 3, 1, 8);
    MTILE(1, 0, 1, 8);
    MTILE(2, 1, 1, 8);
    MTILE(3, 2, 1, 8);
  }
  MTILE(0, 3, 1, 8);                            // tile 128, stage 131
  MTILE(1, 0, 0, 4);                            // tile 129
  MTILE(2, 0, 0, 0);                            // tile 130
  MTILE(3, 0, 0, 0);                            // tile 131

  // epilogue: bias add, f32 store
#pragma unroll
  for (int ni = 0; ni < 4; ++ni) {
    const int c = col0 + wn * 64 + ni * 16 + (lane & 15);
    const float bv = bias[c];
#pragma unroll
    for (int mi = 0; mi < 8; ++mi) {
#pragma unroll
      for (int i = 0; i < 4; ++i) {
        int r = row0 + wm * 128 + mi * 16 + ks * 4 + i;
        Out[(size_t)r * D_OUT + c] = acc[mi][ni][i] + bv;
      }
    }
  }
}

extern "C" void kernel_launch(void* const* d_in, const int* in_sizes, int n_in,
                              void* d_out, int out_size, void* d_ws, size_t ws_size,
                              hipStream_t stream) {
  const float* x        = (const float*)d_in[0];
  const float* W_base   = (const float*)d_in[1];
  const float* b_base   = (const float*)d_in[2];
  const float* W_router = (const float*)d_in[3];
  const float* A_stack  = (const float*)d_in[4];
  const float* B_stack  = (const float*)d_in[5];
  float* out = (float*)d_out;

  char* ws = (char*)d_ws;
  unsigned short* Xcat = (unsigned short*)(ws);                 // 69,206,016 B
  unsigned short* Wcat = (unsigned short*)(ws + 69206016);      // 34,603,008 B
  unsigned short* Ab   = (unsigned short*)(ws + 103809024);     //  1,048,576 B
  float*          Comb = (float*)(ws + 104857600);              //    262,144 B
  // total ws use: 105,119,744 B (same as R1/R2 footprint)

  hipLaunchKernelGGL(prep_kernel, dim3(2048), dim3(256), 0, stream,
                     W_base, A_stack, B_stack, Wcat, Ab);
  hipLaunchKernelGGL(router_kernel, dim3(512), dim3(256), 0, stream,
                     x, W_router, Xcat, Comb);
  hipLaunchKernelGGL(h_gemm_kernel, dim3(256), dim3(256), 0, stream,
                     Xcat, Ab, Comb);
  hipLaunchKernelGGL(main_gemm_kernel, dim3(512), dim3(512), 0, stream,
                     Xcat, Wcat, b_base, out);
}